// Round 5
// baseline (100.531 us; speedup 1.0000x reference)
//
#include <hip/hip_runtime.h>

// extract_patches: in [B=16, W=112, H=112, D=128] f32
// K0=K1=4, S0=S1=2 -> nh=nv=55
// out[b][ph*55+pv][(k0*4+k1)*128 + d] = in[b][ph*2+k0][pv*2+k1][d]
// out: [16, 3025, 2048] f32
//
// R5: scatter formulation (input read exactly once, each float4 stored to
// its <=4 output homes; bijective map -> every output written exactly once).
// Single change vs R4: PLAIN stores instead of nontemporal. In the scatter
// form the input has no reuse, so NT's cache-protection value is zero, and
// NT may reduce L2 write-coalescing into large HBM bursts (fillBuffer's
// 7 TB/s and the 6.29 TB/s copy ceiling both use plain stores).
// One block per input row (b,w): 512 threads x 7 iters cover 112 h x 32 d4.

typedef float f32x4 __attribute__((ext_vector_type(4)));

#define W_IN 112
#define H_IN 112
#define NH 55
#define NV 55
#define D4 32     // 128 floats / 4
#define ITERS 7   // 112 h / 16 h-per-iter

__global__ __launch_bounds__(512) void scatter_kernel(
    const float* __restrict__ in, float* __restrict__ out) {
    const int blk = blockIdx.x;            // b*112 + w
    const int w = blk % W_IN;
    const int b = blk / W_IN;
    const int tid = threadIdx.x;
    const int d4 = tid & 31;
    const int dh = tid >> 5;               // 0..15

    // k0 candidates for this row (wave-uniform): k0 == w (mod 2)
    const int k0a = w & 1;
    const int pha = (w - k0a) >> 1;        // == 55 (invalid) when w >= 110
    const int k0b = k0a + 2;
    const int phb = pha - 1;               // == -1 (invalid) when w <= 1
    const bool vA = (pha < NH);
    const bool vB = (phb >= 0);
    const int pha_c = vA ? pha : 0;        // clamp for safe address calc
    const int phb_c = vB ? phb : 0;

    const f32x4* __restrict__ src4 = reinterpret_cast<const f32x4*>(in);
    f32x4* __restrict__ dst4 = reinterpret_cast<f32x4*>(out);

    f32x4 v[ITERS];
    #pragma unroll
    for (int it = 0; it < ITERS; ++it) {
        const int h = it * 16 + dh;
        v[it] = src4[(size_t)(blk * H_IN + h) * D4 + d4];
    }

    // patch float4 size = 16*128/4 = 512; out idx = patch*512 + (k0*4+k1)*32 + d4
    const size_t baseA = (size_t)(b * (NH * NV) + pha_c * NV) * 512 + (size_t)(k0a * 128) + d4;
    const size_t baseB = (size_t)(b * (NH * NV) + phb_c * NV) * 512 + (size_t)(k0b * 128) + d4;

    #pragma unroll
    for (int it = 0; it < ITERS; ++it) {
        const int h = it * 16 + dh;
        const int k1a = h & 1;
        const int pva = (h - k1a) >> 1;    // == 55 (invalid) when h >= 110
        const int pvb = pva - 1;           // == -1 (invalid) when h <= 1
        const int k1b = k1a + 2;
        const bool vC = (pva < NV);
        const bool vD = (pvb >= 0);
        const size_t offC = (size_t)(vC ? pva : 0) * 512 + (size_t)(k1a * 32);
        const size_t offD = (size_t)(vD ? pvb : 0) * 512 + (size_t)(k1b * 32);
        if (vA) {
            if (vC) dst4[baseA + offC] = v[it];
            if (vD) dst4[baseA + offD] = v[it];
        }
        if (vB) {
            if (vC) dst4[baseB + offC] = v[it];
            if (vD) dst4[baseB + offD] = v[it];
        }
    }
}

extern "C" void kernel_launch(void* const* d_in, const int* in_sizes, int n_in,
                              void* d_out, int out_size, void* d_ws, size_t ws_size,
                              hipStream_t stream) {
    const float* in = (const float*)d_in[0];
    float* out = (float*)d_out;

    const int nblocks = 16 * W_IN;          // 1792 blocks, one per input row
    scatter_kernel<<<nblocks, 512, 0, stream>>>(in, out);
}

// Round 6
// 99.544 us; speedup vs baseline: 1.0099x; 1.0099x over previous
//
#include <hip/hip_runtime.h>

// extract_patches: in [B=16, W=112, H=112, D=128] f32
// K0=K1=4, S0=S1=2 -> nh=nv=55
// out[b][ph*55+pv][(k0*4+k1)*128 + d] = in[b][ph*2+k0][pv*2+k1][d]
// out: [16, 3025, 2048] f32
//
// R6: R4 scatter formulation (NT stores — R5 proved plain stores cost 12%:
// write-allocate of the 397 MB stream thrashes L2) + NT LOADS: the input is
// read exactly once, so L2-allocating it is pure pollution next to the
// NT-store stream.
// Wave-level audit: reads are 1KB/instr; all 4 store streams are 1KB
// contiguous per wave instr (dh even/odd pair -> adjacent 512B k1-slices).

typedef float f32x4 __attribute__((ext_vector_type(4)));

#define W_IN 112
#define H_IN 112
#define NH 55
#define NV 55
#define D4 32     // 128 floats / 4
#define ITERS 7   // 112 h / 16 h-per-iter

__global__ __launch_bounds__(512) void scatter_kernel(
    const float* __restrict__ in, float* __restrict__ out) {
    const int blk = blockIdx.x;            // b*112 + w
    const int w = blk % W_IN;
    const int b = blk / W_IN;
    const int tid = threadIdx.x;
    const int d4 = tid & 31;
    const int dh = tid >> 5;               // 0..15

    // k0 candidates for this row (wave-uniform): k0 == w (mod 2)
    const int k0a = w & 1;
    const int pha = (w - k0a) >> 1;        // == 55 (invalid) when w >= 110
    const int k0b = k0a + 2;
    const int phb = pha - 1;               // == -1 (invalid) when w <= 1
    const bool vA = (pha < NH);
    const bool vB = (phb >= 0);
    const int pha_c = vA ? pha : 0;        // clamp for safe address calc
    const int phb_c = vB ? phb : 0;

    const f32x4* __restrict__ src4 = reinterpret_cast<const f32x4*>(in);
    f32x4* __restrict__ dst4 = reinterpret_cast<f32x4*>(out);

    f32x4 v[ITERS];
    #pragma unroll
    for (int it = 0; it < ITERS; ++it) {
        const int h = it * 16 + dh;
        v[it] = __builtin_nontemporal_load(&src4[(size_t)(blk * H_IN + h) * D4 + d4]);
    }

    // patch float4 size = 16*128/4 = 512; out idx = patch*512 + (k0*4+k1)*32 + d4
    const size_t baseA = (size_t)(b * (NH * NV) + pha_c * NV) * 512 + (size_t)(k0a * 128) + d4;
    const size_t baseB = (size_t)(b * (NH * NV) + phb_c * NV) * 512 + (size_t)(k0b * 128) + d4;

    #pragma unroll
    for (int it = 0; it < ITERS; ++it) {
        const int h = it * 16 + dh;
        const int k1a = h & 1;
        const int pva = (h - k1a) >> 1;    // == 55 (invalid) when h >= 110
        const int pvb = pva - 1;           // == -1 (invalid) when h <= 1
        const int k1b = k1a + 2;
        const bool vC = (pva < NV);
        const bool vD = (pvb >= 0);
        const size_t offC = (size_t)(vC ? pva : 0) * 512 + (size_t)(k1a * 32);
        const size_t offD = (size_t)(vD ? pvb : 0) * 512 + (size_t)(k1b * 32);
        if (vA) {
            if (vC) __builtin_nontemporal_store(v[it], &dst4[baseA + offC]);
            if (vD) __builtin_nontemporal_store(v[it], &dst4[baseA + offD]);
        }
        if (vB) {
            if (vC) __builtin_nontemporal_store(v[it], &dst4[baseB + offC]);
            if (vD) __builtin_nontemporal_store(v[it], &dst4[baseB + offD]);
        }
    }
}

extern "C" void kernel_launch(void* const* d_in, const int* in_sizes, int n_in,
                              void* d_out, int out_size, void* d_ws, size_t ws_size,
                              hipStream_t stream) {
    const float* in = (const float*)d_in[0];
    float* out = (float*)d_out;

    const int nblocks = 16 * W_IN;          // 1792 blocks, one per input row
    scatter_kernel<<<nblocks, 512, 0, stream>>>(in, out);
}

// Round 7
// 92.184 us; speedup vs baseline: 1.0905x; 1.0798x over previous
//
#include <hip/hip_runtime.h>

// extract_patches: in [B=16, W=112, H=112, D=128] f32
// K0=K1=4, S0=S1=2 -> nh=nv=55
// out[b][ph*55+pv][(k0*4+k1)*128 + d] = in[b][ph*2+k0][pv*2+k1][d]
// out: [16, 3025, 2048] f32
//
// R7: scatter formulation, NT stores + plain loads (R5/R6 bracketed: NT
// store +12%, NT load -11%). Single change vs R4: 256-thread blocks
// (4 waves) so all 7 blocks/CU are co-resident in ONE generation
// (512-thread blocks cap at 4 blocks/CU -> 4+3 two-generation dispatch).
// Row processed in two half-batches of 7 loads/stores (7-deep MLP, VGPR
// bounded). Each wave still covers an (even,odd) h-pair -> every store
// stream is 1KB contiguous per instruction.

typedef float f32x4 __attribute__((ext_vector_type(4)));

#define W_IN 112
#define H_IN 112
#define NH 55
#define NV 55
#define D4 32     // 128 floats / 4
#define HB 7      // iters per half; h = half*56 + it*8 + dh

__global__ __launch_bounds__(256) void scatter_kernel(
    const float* __restrict__ in, float* __restrict__ out) {
    const int blk = blockIdx.x;            // b*112 + w
    const int w = blk % W_IN;
    const int b = blk / W_IN;
    const int tid = threadIdx.x;
    const int d4 = tid & 31;
    const int dh = tid >> 5;               // 0..7

    // k0 candidates for this row (block-uniform): k0 == w (mod 2)
    const int k0a = w & 1;
    const int pha = (w - k0a) >> 1;        // == 55 (invalid) when w >= 110
    const int k0b = k0a + 2;
    const int phb = pha - 1;               // == -1 (invalid) when w <= 1
    const bool vA = (pha < NH);
    const bool vB = (phb >= 0);
    const int pha_c = vA ? pha : 0;        // clamp for safe address calc
    const int phb_c = vB ? phb : 0;

    const f32x4* __restrict__ src4 = reinterpret_cast<const f32x4*>(in);
    f32x4* __restrict__ dst4 = reinterpret_cast<f32x4*>(out);

    // patch float4 size = 16*128/4 = 512; out idx = patch*512 + (k0*4+k1)*32 + d4
    const size_t baseA = (size_t)(b * (NH * NV) + pha_c * NV) * 512 + (size_t)(k0a * 128) + d4;
    const size_t baseB = (size_t)(b * (NH * NV) + phb_c * NV) * 512 + (size_t)(k0b * 128) + d4;

    #pragma unroll
    for (int half = 0; half < 2; ++half) {
        f32x4 v[HB];
        #pragma unroll
        for (int it = 0; it < HB; ++it) {
            const int h = half * 56 + it * 8 + dh;
            v[it] = src4[(size_t)(blk * H_IN + h) * D4 + d4];
        }

        #pragma unroll
        for (int it = 0; it < HB; ++it) {
            const int h = half * 56 + it * 8 + dh;
            const int k1a = h & 1;
            const int pva = (h - k1a) >> 1;    // == 55 (invalid) when h >= 110
            const int pvb = pva - 1;           // == -1 (invalid) when h <= 1
            const int k1b = k1a + 2;
            const bool vC = (pva < NV);
            const bool vD = (pvb >= 0);
            const size_t offC = (size_t)(vC ? pva : 0) * 512 + (size_t)(k1a * 32);
            const size_t offD = (size_t)(vD ? pvb : 0) * 512 + (size_t)(k1b * 32);
            if (vA) {
                if (vC) __builtin_nontemporal_store(v[it], &dst4[baseA + offC]);
                if (vD) __builtin_nontemporal_store(v[it], &dst4[baseA + offD]);
            }
            if (vB) {
                if (vC) __builtin_nontemporal_store(v[it], &dst4[baseB + offC]);
                if (vD) __builtin_nontemporal_store(v[it], &dst4[baseB + offD]);
            }
        }
    }
}

extern "C" void kernel_launch(void* const* d_in, const int* in_sizes, int n_in,
                              void* d_out, int out_size, void* d_ws, size_t ws_size,
                              hipStream_t stream) {
    const float* in = (const float*)d_in[0];
    float* out = (float*)d_out;

    const int nblocks = 16 * W_IN;          // 1792 blocks, one per input row
    scatter_kernel<<<nblocks, 256, 0, stream>>>(in, out);
}

// Round 8
// 84.070 us; speedup vs baseline: 1.1958x; 1.0965x over previous
//
#include <hip/hip_runtime.h>

// extract_patches: in [B=16, W=112, H=112, D=128] f32
// K0=K1=4, S0=S1=2 -> nh=nv=55
// out[b][ph*55+pv][(k0*4+k1)*128 + d] = in[b][ph*2+k0][pv*2+k1][d]
// out: [16, 3025, 2048] f32
//
// R8 = R4 FINAL (best: 88.2 us, 5.67 TB/s effective on the minimal 500 MB).
// Scatter formulation: each input float4 loaded exactly once, NT-stored to
// its <=4 output homes (bijective map -> each output written exactly once).
// A/B history: gather 94.3 -> scatter 88.2; NT store +12% (write-allocate
// thrash of 397 MB stream); NT load -11%; plain store -12%; 256-thr blocks
// -4%. One block per input row (b,w): 512 threads x 7 iters, loads issued
// up front (7-deep MLP); all validity predicates wave-uniform; every store
// stream 1KB contiguous per wave instruction.

typedef float f32x4 __attribute__((ext_vector_type(4)));

#define W_IN 112
#define H_IN 112
#define NH 55
#define NV 55
#define D4 32     // 128 floats / 4
#define ITERS 7   // 112 h / 16 h-per-iter

__global__ __launch_bounds__(512) void scatter_kernel(
    const float* __restrict__ in, float* __restrict__ out) {
    const int blk = blockIdx.x;            // b*112 + w
    const int w = blk % W_IN;
    const int b = blk / W_IN;
    const int tid = threadIdx.x;
    const int d4 = tid & 31;
    const int dh = tid >> 5;               // 0..15

    // k0 candidates for this row (wave-uniform): k0 == w (mod 2)
    const int k0a = w & 1;
    const int pha = (w - k0a) >> 1;        // == 55 (invalid) when w >= 110
    const int k0b = k0a + 2;
    const int phb = pha - 1;               // == -1 (invalid) when w <= 1
    const bool vA = (pha < NH);
    const bool vB = (phb >= 0);
    const int pha_c = vA ? pha : 0;        // clamp for safe address calc
    const int phb_c = vB ? phb : 0;

    const f32x4* __restrict__ src4 = reinterpret_cast<const f32x4*>(in);
    f32x4* __restrict__ dst4 = reinterpret_cast<f32x4*>(out);

    f32x4 v[ITERS];
    #pragma unroll
    for (int it = 0; it < ITERS; ++it) {
        const int h = it * 16 + dh;
        v[it] = src4[(size_t)(blk * H_IN + h) * D4 + d4];
    }

    // patch float4 size = 16*128/4 = 512; out idx = patch*512 + (k0*4+k1)*32 + d4
    const size_t baseA = (size_t)(b * (NH * NV) + pha_c * NV) * 512 + (size_t)(k0a * 128) + d4;
    const size_t baseB = (size_t)(b * (NH * NV) + phb_c * NV) * 512 + (size_t)(k0b * 128) + d4;

    #pragma unroll
    for (int it = 0; it < ITERS; ++it) {
        const int h = it * 16 + dh;
        const int k1a = h & 1;
        const int pva = (h - k1a) >> 1;    // == 55 (invalid) when h >= 110
        const int pvb = pva - 1;           // == -1 (invalid) when h <= 1
        const int k1b = k1a + 2;
        const bool vC = (pva < NV);
        const bool vD = (pvb >= 0);
        const size_t offC = (size_t)(vC ? pva : 0) * 512 + (size_t)(k1a * 32);
        const size_t offD = (size_t)(vD ? pvb : 0) * 512 + (size_t)(k1b * 32);
        if (vA) {
            if (vC) __builtin_nontemporal_store(v[it], &dst4[baseA + offC]);
            if (vD) __builtin_nontemporal_store(v[it], &dst4[baseA + offD]);
        }
        if (vB) {
            if (vC) __builtin_nontemporal_store(v[it], &dst4[baseB + offC]);
            if (vD) __builtin_nontemporal_store(v[it], &dst4[baseB + offD]);
        }
    }
}

extern "C" void kernel_launch(void* const* d_in, const int* in_sizes, int n_in,
                              void* d_out, int out_size, void* d_ws, size_t ws_size,
                              hipStream_t stream) {
    const float* in = (const float*)d_in[0];
    float* out = (float*)d_out;

    const int nblocks = 16 * W_IN;          // 1792 blocks, one per input row
    scatter_kernel<<<nblocks, 512, 0, stream>>>(in, out);
}